// Round 10
// baseline (538.251 us; speedup 1.0000x reference)
//
#include <hip/hip_runtime.h>
#include <math.h>

#define N_NODES_C 100000
#define N_EDGES_C 3200000
// D_NODE=16, D_EDGE=8, D_HIDDEN=16

#define NORM_MSG_TP 0.08838834764831845f   // 1/sqrt(16*8)
#define NORM_UPD_TP 0.0625f                // 1/sqrt(16*16)
#define NORM_LIN    0.25f                  // 1/sqrt(16)

typedef float f32x4 __attribute__((ext_vector_type(4)));
typedef short bf16x8 __attribute__((ext_vector_type(8)));
typedef int   int4v  __attribute__((ext_vector_type(4)));

__device__ __forceinline__ float silu_f(float v) {
  return v / (1.0f + __expf(-v));
}

__device__ __forceinline__ void atomic_add_hw(float* p, float v) {
  unsafeAtomicAdd(p, v);
}

// float -> bf16 bits (round to nearest even)
__device__ __forceinline__ unsigned int bf16_bits(float f) {
  unsigned int b = __float_as_uint(f);
  return (b + 0x7fffu + ((b >> 16) & 1u)) >> 16;
}
__device__ __forceinline__ unsigned int pack_bf16x2(float lo, float hi) {
  return bf16_bits(lo) | (bf16_bits(hi) << 16);
}
__device__ __forceinline__ float unlo(unsigned int w) { return __uint_as_float(w << 16); }
__device__ __forceinline__ float unhi(unsigned int w) { return __uint_as_float(w & 0xffff0000u); }

// ---------------- CSR build ----------------

__global__ __launch_bounds__(256) void zero_ints(int* __restrict__ p, int n) {
  int i = blockIdx.x * 256 + threadIdx.x;
  if (i < n) p[i] = 0;
}

__global__ __launch_bounds__(256) void hist_kernel(
    const int* __restrict__ row, int* __restrict__ cnt) {
  int e = blockIdx.x * 256 + threadIdx.x;   // grid exact: E/256
  atomicAdd(&cnt[row[e]], 1);
}

__global__ __launch_bounds__(256) void scan_block(
    const int* __restrict__ cnt, int* __restrict__ off, int* __restrict__ bsum, int n) {
  __shared__ int s[256];
  const int t = threadIdx.x;
  const int i = blockIdx.x * 256 + t;
  const int v = (i < n) ? cnt[i] : 0;
  s[t] = v;
  __syncthreads();
#pragma unroll
  for (int o = 1; o < 256; o <<= 1) {
    int tv = (t >= o) ? s[t - o] : 0;
    __syncthreads();
    s[t] += tv;
    __syncthreads();
  }
  if (i < n) off[i] = s[t] - v;
  if (t == 255) bsum[blockIdx.x] = s[255];
}

__global__ void scan_bsum(int* __restrict__ bsum, int nb) {
  __shared__ int s[512];
  const int t = threadIdx.x;
  const int v = (t < nb) ? bsum[t] : 0;
  s[t] = v;
  __syncthreads();
#pragma unroll
  for (int o = 1; o < 512; o <<= 1) {
    int tv = (t >= o) ? s[t - o] : 0;
    __syncthreads();
    s[t] += tv;
    __syncthreads();
  }
  if (t < nb) bsum[t] = s[t] - v;
}

__global__ __launch_bounds__(256) void scan_add(
    int* __restrict__ off, const int* __restrict__ bsum, int n, int total) {
  int i = blockIdx.x * 256 + threadIdx.x;
  if (i < n) off[i] += bsum[blockIdx.x];
  if (i == 0) off[n] = total;
}

// perm-only sorted placement: 4B/edge random writes into 12.8 MB (L2-merged)
__global__ __launch_bounds__(256) void placeP_kernel(
    const int* __restrict__ eidx, const int* __restrict__ off,
    int* __restrict__ cnt, int* __restrict__ perm) {
  int e = blockIdx.x * 256 + threadIdx.x;   // grid exact
  const int r = eidx[e];
  const int p = off[r] + atomicSub(&cnt[r], 1) - 1;
  perm[p] = e;
}

// ---------------- x -> bf16 table (3.2 MB, L2-resident) ----------------

__global__ __launch_bounds__(256) void xcast_kernel(
    const float* __restrict__ x, unsigned short* __restrict__ xb) {
  const int i = blockIdx.x * 256 + threadIdx.x;   // one thread per 8 elems
  if (i < N_NODES_C * 2) {
    const float4 a = *reinterpret_cast<const float4*>(x + (size_t)i * 8);
    const float4 b = *reinterpret_cast<const float4*>(x + (size_t)i * 8 + 4);
    uint4 w;
    w.x = pack_bf16x2(a.x, a.y); w.y = pack_bf16x2(a.z, a.w);
    w.z = pack_bf16x2(b.x, b.y); w.w = pack_bf16x2(b.z, b.w);
    *reinterpret_cast<uint4*>(xb + (size_t)i * 8) = w;
  }
}

// ---------------- msg: MFMA messages in EDGE order, linear 512B/tile store ----------------
// K reordered as k = j*16 + i (same as R9). Lane (r,g): i = 8*(g&1)+t, j = 2q+(g>>1).
// 2-deep pipeline on the eidx -> xb dependent chain. No atomics, no scatter.

#define COLS_TILE(T, CC) do {                                        \
    if (g == 0) CC = eidx[N_EDGES_C + (T) * 16 + r];                 \
  } while (0)

#define GATH_TILE(T, CC, XH, F4) do {                                \
    const int e_ = (T) * 16 + r;                                     \
    const int c_ = __shfl(CC, r);                                    \
    if (g < 2) {                                                     \
      XH = *reinterpret_cast<const uint4*>(xb + (size_t)c_ * 16 + g * 8); \
      F4 = *reinterpret_cast<const float4*>(ea + (size_t)e_ * 8 + g * 4); \
    }                                                                \
  } while (0)

__global__ __launch_bounds__(256) void msg_kernel(
    const int*   __restrict__ eidx,   // [2,E]
    const float* __restrict__ ea,     // [E,8] fp32
    const float* __restrict__ Wtp,    // [16,8,16]
    const unsigned short* __restrict__ xb,  // [N,16] bf16
    unsigned int* __restrict__ msgb)  // [E*8] words: edge e = 32B bf16x16, edge order
{
  __shared__ float sm[4][16][20];     // stride 20: 16B-aligned rows, 2-way banks
  const int lane  = threadIdx.x & 63;
  const int wv    = threadIdx.x >> 6;
  const int r     = lane & 15;
  const int g     = lane >> 4;
  const int gsel  = g >> 1;
  const int ghalf = g & 1;

  // B frag: bq[q][t] = Wtp[i=8*ghalf+t][j=2q+gsel][h=r]
  bf16x8 bq[4];
#pragma unroll
  for (int q = 0; q < 4; ++q) {
#pragma unroll
    for (int t = 0; t < 8; ++t) {
      const float w = Wtp[(8 * ghalf + t) * 128 + (2 * q + gsel) * 16 + r];
      bq[q][t] = (short)bf16_bits(w);
    }
  }

  const int s = gridDim.x * 4;
  const int wid = blockIdx.x * 4 + wv;
  const int ntiles = N_EDGES_C / 16;  // 200000

  int cc_a = 0, cc_b = 0;
  uint4 xh_a; xh_a.x = xh_a.y = xh_a.z = xh_a.w = 0;
  float4 f4_a = make_float4(0.f, 0.f, 0.f, 0.f);

  if (wid < ntiles)     COLS_TILE(wid, cc_a);
  if (wid + s < ntiles) COLS_TILE(wid + s, cc_b);
  if (wid < ntiles)     GATH_TILE(wid, cc_a, xh_a, f4_a);

  for (int t = wid; t < ntiles; t += s) {
    // depth-2: next-next column indices
    int cc_c = 0;
    if (t + 2 * s < ntiles) COLS_TILE(t + 2 * s, cc_c);
    // depth-1: next-tile gathers
    uint4 xh_b; xh_b.x = xh_b.y = xh_b.z = xh_b.w = 0;
    float4 f4_b = make_float4(0.f, 0.f, 0.f, 0.f);
    if (t + s < ntiles) GATH_TILE(t + s, cc_b, xh_b, f4_b);

    // ---- compute tile t ----
    uint4 xh;
    xh.x = (unsigned)__shfl((int)xh_a.x, ghalf * 16 + r);
    xh.y = (unsigned)__shfl((int)xh_a.y, ghalf * 16 + r);
    xh.z = (unsigned)__shfl((int)xh_a.z, ghalf * 16 + r);
    xh.w = (unsigned)__shfl((int)xh_a.w, ghalf * 16 + r);
    float xf[8];
    xf[0] = unlo(xh.x); xf[1] = unhi(xh.x);
    xf[2] = unlo(xh.y); xf[3] = unhi(xh.y);
    xf[4] = unlo(xh.z); xf[5] = unhi(xh.z);
    xf[6] = unlo(xh.w); xf[7] = unhi(xh.w);
    const float a0 = __shfl(f4_a.x, r),      a1 = __shfl(f4_a.y, r);
    const float a2 = __shfl(f4_a.z, r),      a3 = __shfl(f4_a.w, r);
    const float b0 = __shfl(f4_a.x, 16 + r), b1 = __shfl(f4_a.y, 16 + r);
    const float b2 = __shfl(f4_a.z, 16 + r), b3 = __shfl(f4_a.w, 16 + r);
    float eq[4];
    eq[0] = gsel ? a1 : a0;  eq[1] = gsel ? a3 : a2;
    eq[2] = gsel ? b1 : b0;  eq[3] = gsel ? b3 : b2;

    f32x4 acc = {0.f, 0.f, 0.f, 0.f};
#pragma unroll
    for (int q = 0; q < 4; ++q) {
      const float e_ = eq[q];
      const unsigned u0 = __float_as_uint(xf[0] * e_) + 0x8000u;
      const unsigned u1 = __float_as_uint(xf[1] * e_) + 0x8000u;
      const unsigned u2 = __float_as_uint(xf[2] * e_) + 0x8000u;
      const unsigned u3 = __float_as_uint(xf[3] * e_) + 0x8000u;
      const unsigned u4 = __float_as_uint(xf[4] * e_) + 0x8000u;
      const unsigned u5 = __float_as_uint(xf[5] * e_) + 0x8000u;
      const unsigned u6 = __float_as_uint(xf[6] * e_) + 0x8000u;
      const unsigned u7 = __float_as_uint(xf[7] * e_) + 0x8000u;
      int4v iv;
      iv.x = (int)__builtin_amdgcn_perm(u1, u0, 0x07060302u);
      iv.y = (int)__builtin_amdgcn_perm(u3, u2, 0x07060302u);
      iv.z = (int)__builtin_amdgcn_perm(u5, u4, 0x07060302u);
      iv.w = (int)__builtin_amdgcn_perm(u7, u6, 0x07060302u);
      union { int4v i; bf16x8 h; } cv; cv.i = iv;
      acc = __builtin_amdgcn_mfma_f32_16x16x32_bf16(cv.h, bq[q], acc, 0, 0, 0);
    }

    // silu + 16x16 transpose via padded per-wave LDS tile
#pragma unroll
    for (int j2 = 0; j2 < 4; ++j2)
      sm[wv][g * 4 + j2][r] = silu_f(acc[j2] * NORM_MSG_TP);

    asm volatile("s_waitcnt lgkmcnt(0)" ::: "memory");
    __builtin_amdgcn_sched_barrier(0);

    // linear store: tile t -> bytes [t*512, t*512+512), full lines
    const int rr  = lane >> 2;
    const int wsl = lane & 3;
    const float4 v4 = *reinterpret_cast<const float4*>(&sm[wv][rr][wsl * 4]);
    uint2 wout;
    wout.x = pack_bf16x2(v4.x, v4.y);
    wout.y = pack_bf16x2(v4.z, v4.w);
    *reinterpret_cast<uint2*>(&msgb[(size_t)(t * 16 + rr) * 8 + wsl * 2]) = wout;

    // rotate pipeline state
    xh_a = xh_b; f4_a = f4_b; cc_b = cc_c;
  }
}

// ---------------- agg4: perm-indirect gather of edge-order messages + Wlin ----------------

__global__ __launch_bounds__(256) void agg4_kernel(
    const float* __restrict__ Wlin,   // [16,16]
    const int*   __restrict__ perm,   // [E] edge id at sorted pos (linear read)
    const unsigned int* __restrict__ msgb,  // [E*8] edge-order messages
    const int*   __restrict__ off,    // [N+1]
    float*       __restrict__ agg)    // [N,16]
{
  __shared__ float sL[256];
  if (threadIdx.x < 256) sL[threadIdx.x] = Wlin[threadIdx.x];
  __syncthreads();

  const int slane = threadIdx.x & 15;
  const int wsel  = slane >> 1;
  const int n = blockIdx.x * 16 + (threadIdx.x >> 4);   // grid exact: N/16

  const int off0 = off[n];
  const int off1 = off[n + 1];

  float acc = 0.f;
  int p = off0;
  for (; p + 3 < off1; p += 4) {
    const int e0 = perm[p], e1 = perm[p + 1], e2 = perm[p + 2], e3 = perm[p + 3];
    const unsigned w0 = msgb[(size_t)e0 * 8 + wsel];
    const unsigned w1 = msgb[(size_t)e1 * 8 + wsel];
    const unsigned w2 = msgb[(size_t)e2 * 8 + wsel];
    const unsigned w3 = msgb[(size_t)e3 * 8 + wsel];
    if (slane & 1) acc += unhi(w0) + unhi(w1) + unhi(w2) + unhi(w3);
    else           acc += unlo(w0) + unlo(w1) + unlo(w2) + unlo(w3);
  }
  for (; p < off1; ++p) {
    const unsigned w = msgb[(size_t)perm[p] * 8 + wsel];
    acc += (slane & 1) ? unhi(w) : unlo(w);
  }

  float a = 0.f;
#pragma unroll
  for (int h = 0; h < 16; ++h) {
    const float v = __shfl(acc, h, 16);
    a = fmaf(v, sL[h * 16 + slane], a);
  }
  agg[(size_t)n * 16 + slane] = a * NORM_LIN;
}

// ---------------- Tier B (R6): eab/colp split path ----------------

__global__ __launch_bounds__(256) void tbuild_kernel(
    const float* __restrict__ x, const float* __restrict__ Wtp,
    uint4* __restrict__ Tb)
{
  __shared__ float sWT[16 * 132];
  for (int idx = threadIdx.x; idx < 2048; idx += 256) {
    const int i = idx >> 7, j = (idx >> 4) & 7, h = idx & 15;
    sWT[h * 132 + i * 8 + j] = Wtp[idx];
  }
  __syncthreads();

  const int slane = threadIdx.x & 15;
  const int n = blockIdx.x * 16 + (threadIdx.x >> 4);

  float xr[16];
  const float4* xp = reinterpret_cast<const float4*>(x + (size_t)n * 16);
#pragma unroll
  for (int q = 0; q < 4; ++q) {
    float4 v = xp[q];
    xr[q*4+0] = v.x; xr[q*4+1] = v.y; xr[q*4+2] = v.z; xr[q*4+3] = v.w;
  }

  float t[8];
#pragma unroll
  for (int j = 0; j < 8; ++j) t[j] = 0.f;
#pragma unroll
  for (int i = 0; i < 16; ++i) {
    const float xi = xr[i];
    const float4 wa = *reinterpret_cast<const float4*>(&sWT[slane * 132 + i * 8]);
    const float4 wb = *reinterpret_cast<const float4*>(&sWT[slane * 132 + i * 8 + 4]);
    t[0] = fmaf(xi, wa.x, t[0]); t[1] = fmaf(xi, wa.y, t[1]);
    t[2] = fmaf(xi, wa.z, t[2]); t[3] = fmaf(xi, wa.w, t[3]);
    t[4] = fmaf(xi, wb.x, t[4]); t[5] = fmaf(xi, wb.y, t[5]);
    t[6] = fmaf(xi, wb.z, t[6]); t[7] = fmaf(xi, wb.w, t[7]);
  }
  uint4 w;
  w.x = pack_bf16x2(t[0], t[1]);
  w.y = pack_bf16x2(t[2], t[3]);
  w.z = pack_bf16x2(t[4], t[5]);
  w.w = pack_bf16x2(t[6], t[7]);
  Tb[(size_t)n * 16 + slane] = w;
}

__global__ __launch_bounds__(256) void place_kernel(
    const int* __restrict__ eidx, const float* __restrict__ ea,
    const int* __restrict__ off, int* __restrict__ cnt,
    int* __restrict__ colp, uint4* __restrict__ eab) {
  int e = blockIdx.x * 256 + threadIdx.x;
  const int r = eidx[e];
  const int old = atomicSub(&cnt[r], 1);
  const int p = off[r] + old - 1;
  colp[p] = eidx[N_EDGES_C + e];
  const float4* ep = reinterpret_cast<const float4*>(ea + (size_t)e * 8);
  const float4 a = ep[0];
  const float4 b = ep[1];
  uint4 w;
  w.x = pack_bf16x2(a.x, a.y);
  w.y = pack_bf16x2(a.z, a.w);
  w.z = pack_bf16x2(b.x, b.y);
  w.w = pack_bf16x2(b.z, b.w);
  eab[p] = w;
}

__global__ __launch_bounds__(256) void agg2_kernel(
    const float* __restrict__ Wlin, const int* __restrict__ colp,
    const uint4* __restrict__ eab, const uint4* __restrict__ Tb,
    const int* __restrict__ off, float* __restrict__ agg)
{
  __shared__ float sL[256];
  if (threadIdx.x < 256) sL[threadIdx.x] = Wlin[threadIdx.x];
  __syncthreads();

  const int slane = threadIdx.x & 15;
  const int n = blockIdx.x * 16 + (threadIdx.x >> 4);

  const int off0 = off[n];
  const int off1 = off[n + 1];

  float acc = 0.f;
#pragma unroll 2
  for (int p = off0; p < off1; ++p) {
    const int c = colp[p];
    const uint4 tw = Tb[(size_t)c * 16 + slane];
    const uint4 ew = eab[p];
    float m;
    m  = unlo(ew.x) * unlo(tw.x);
    m  = fmaf(unhi(ew.x), unhi(tw.x), m);
    m  = fmaf(unlo(ew.y), unlo(tw.y), m);
    m  = fmaf(unhi(ew.y), unhi(tw.y), m);
    m  = fmaf(unlo(ew.z), unlo(tw.z), m);
    m  = fmaf(unhi(ew.z), unhi(tw.z), m);
    m  = fmaf(unlo(ew.w), unlo(tw.w), m);
    m  = fmaf(unhi(ew.w), unhi(tw.w), m);
    acc += silu_f(m * NORM_MSG_TP);
  }

  float a = 0.f;
#pragma unroll
  for (int h = 0; h < 16; ++h) {
    const float v = __shfl(acc, h, 16);
    a = fmaf(v, sL[h * 16 + slane], a);
  }
  agg[(size_t)n * 16 + slane] = a * NORM_LIN;
}

// ---------------- node update ----------------

__global__ __launch_bounds__(256) void node_kernel(
    const float* __restrict__ x, const float* __restrict__ agg,
    const float* __restrict__ Wtp, const float* __restrict__ Wlin,
    float* __restrict__ out)
{
  __shared__ float sW[4096];
  __shared__ float sL[256];
  for (int t = threadIdx.x; t < 4096; t += 256) sW[t] = Wtp[t];
  sL[threadIdx.x] = Wlin[threadIdx.x];
  __syncthreads();

  const long n = (long)blockIdx.x * 256 + threadIdx.x;
  if (n >= N_NODES_C) return;

  float xr[16], ar[16];
  const float4* xp = reinterpret_cast<const float4*>(x + (size_t)n * 16);
  const float4* ap = reinterpret_cast<const float4*>(agg + (size_t)n * 16);
#pragma unroll
  for (int q = 0; q < 4; ++q) {
    float4 v = xp[q];
    xr[q*4+0] = v.x; xr[q*4+1] = v.y; xr[q*4+2] = v.z; xr[q*4+3] = v.w;
    float4 w = ap[q];
    ar[q*4+0] = w.x; ar[q*4+1] = w.y; ar[q*4+2] = w.z; ar[q*4+3] = w.w;
  }
  float u[16];
#pragma unroll
  for (int k = 0; k < 16; ++k) u[k] = 0.f;
#pragma unroll
  for (int i = 0; i < 16; ++i) {
#pragma unroll
    for (int h = 0; h < 16; ++h) {
      const float p = xr[i] * ar[h];
      const float* w = &sW[(i*16 + h) * 16];
#pragma unroll
      for (int k = 0; k < 16; ++k) u[k] = fmaf(p, w[k], u[k]);
    }
  }
  float g[16];
#pragma unroll
  for (int k = 0; k < 16; ++k) g[k] = silu_f(u[k] * NORM_UPD_TP);
  float res[16];
#pragma unroll
  for (int k2 = 0; k2 < 16; ++k2) {
    float a = 0.f;
#pragma unroll
    for (int k = 0; k < 16; ++k) a = fmaf(g[k], sL[k*16 + k2], a);
    res[k2] = xr[k2] + a * NORM_LIN;
  }
  float4* op = reinterpret_cast<float4*>(out + (size_t)n * 16);
#pragma unroll
  for (int q = 0; q < 4; ++q)
    op[q] = make_float4(res[q*4+0], res[q*4+1], res[q*4+2], res[q*4+3]);
}

// ---------------- Tier C fallback: atomic scatter ----------------

__global__ void zero_f4(float4* __restrict__ p, int n4) {
  int i = blockIdx.x * blockDim.x + threadIdx.x;
  if (i < n4) p[i] = make_float4(0.f, 0.f, 0.f, 0.f);
}

#define EPT 2
__global__ __launch_bounds__(256) void edge_kernel(
    const float* __restrict__ x, const float* __restrict__ ea,
    const float* __restrict__ Wtp, const float* __restrict__ Wlin,
    const int* __restrict__ eidx, float* __restrict__ agg)
{
  __shared__ float sW[2048];
  __shared__ float sL[256];
  for (int t = threadIdx.x; t < 2048; t += 256) sW[t] = Wtp[t];
  sL[threadIdx.x] = Wlin[threadIdx.x];
  __syncthreads();
  const long e0 = ((long)blockIdx.x * 256 + threadIdx.x) * EPT;
  float xr[EPT][16], er[EPT][8];
  int rw[EPT];
#pragma unroll
  for (int e = 0; e < EPT; ++e) {
    const long ei = e0 + e;
    const int c = eidx[N_EDGES_C + ei];
    rw[e] = eidx[ei];
    const float4* xp = reinterpret_cast<const float4*>(x + (size_t)c * 16);
#pragma unroll
    for (int q = 0; q < 4; ++q) {
      float4 v = xp[q];
      xr[e][q*4+0] = v.x; xr[e][q*4+1] = v.y; xr[e][q*4+2] = v.z; xr[e][q*4+3] = v.w;
    }
    const float4* ep = reinterpret_cast<const float4*>(ea + (size_t)ei * 8);
#pragma unroll
    for (int q = 0; q < 2; ++q) {
      float4 v = ep[q];
      er[e][q*4+0] = v.x; er[e][q*4+1] = v.y; er[e][q*4+2] = v.z; er[e][q*4+3] = v.w;
    }
  }
  float m[EPT][16];
#pragma unroll
  for (int e = 0; e < EPT; ++e)
#pragma unroll
    for (int h = 0; h < 16; ++h) m[e][h] = 0.f;
#pragma unroll
  for (int i = 0; i < 16; ++i) {
#pragma unroll
    for (int j = 0; j < 8; ++j) {
      float p[EPT];
#pragma unroll
      for (int e = 0; e < EPT; ++e) p[e] = xr[e][i] * er[e][j];
      const float* w = &sW[(i*8 + j) * 16];
#pragma unroll
      for (int h = 0; h < 16; ++h) {
        const float wv = w[h];
#pragma unroll
        for (int e = 0; e < EPT; ++e) m[e][h] = fmaf(p[e], wv, m[e][h]);
      }
    }
  }
#pragma unroll
  for (int e = 0; e < EPT; ++e) {
    float g[16];
#pragma unroll
    for (int h = 0; h < 16; ++h) g[h] = silu_f(m[e][h] * NORM_MSG_TP);
    float* ap = agg + (size_t)rw[e] * 16;
#pragma unroll
    for (int h2 = 0; h2 < 16; ++h2) {
      float a = 0.f;
#pragma unroll
      for (int h = 0; h < 16; ++h) a = fmaf(g[h], sL[h*16 + h2], a);
      atomic_add_hw(ap + h2, a * NORM_LIN);
    }
  }
}

// ---------------- launch ----------------

extern "C" void kernel_launch(void* const* d_in, const int* in_sizes, int n_in,
                              void* d_out, int out_size, void* d_ws, size_t ws_size,
                              hipStream_t stream) {
  const float* node_features = (const float*)d_in[0];
  const float* edge_attr     = (const float*)d_in[1];
  const float* W_msg_tp      = (const float*)d_in[3];
  const float* W_msg_lin     = (const float*)d_in[4];
  const float* W_upd_tp      = (const float*)d_in[5];
  const float* W_upd_lin     = (const float*)d_in[6];
  const int*   edge_index    = (const int*)d_in[7];
  float* out = (float*)d_out;
  char* ws = (char*)d_ws;

  const int NB_N = (N_NODES_C + 255) / 256;           // 391
  const int NB_E = N_EDGES_C / 256;                   // 12500 exact
  const int NB_G = N_NODES_C / 16;                    // 6250 exact

  // ---- Tier A3: edge-order msg + perm gather (125.6 MB) ----
  const size_t A_OFF  = 0;                            // (N+1) ints
  const size_t A_CNT  = 400128;                       // N ints
  const size_t A_BSUM = 800256;                       // 512 ints
  const size_t A_PERM = 802304;                       // E ints (12.8 MB)
  const size_t A_MSGB = A_PERM + 12800000;            // E*8 uint (102.4 MB)
  const size_t A_XB   = A_MSGB + 102400000;           // N*16 ushort (3.2 MB)
  const size_t A_AGG  = A_XB + 3200000;               // N*16 floats
  const size_t A_NEED = A_AGG + 6400000;              // 125,602,304 B (< 135.2 MB proven)

  // ---- Tier B layout: R6 path (96.8 MB) ----
  const size_t B_OFF  = 0;
  const size_t B_CNT  = 400128;
  const size_t B_BSUM = 800256;
  const size_t B_COLP = 804352;
  const size_t B_EAB  = B_COLP + 12800000;
  const size_t B_T    = B_EAB + 51200000;
  const size_t B_AGG  = B_T + 25600000;
  const size_t B_NEED = B_AGG + 6400000;

  if (ws_size >= A_NEED) {
    int*   off   = (int*)(ws + A_OFF);
    int*   cnt   = (int*)(ws + A_CNT);
    int*   bsum  = (int*)(ws + A_BSUM);
    int*   perm  = (int*)(ws + A_PERM);
    unsigned int* msgb = (unsigned int*)(ws + A_MSGB);
    unsigned short* xb = (unsigned short*)(ws + A_XB);
    float* agg   = (float*)(ws + A_AGG);

    hipLaunchKernelGGL(zero_ints, dim3(NB_N), dim3(256), 0, stream, cnt, N_NODES_C);
    hipLaunchKernelGGL(hist_kernel, dim3(NB_E), dim3(256), 0, stream, edge_index, cnt);
    hipLaunchKernelGGL(scan_block, dim3(NB_N), dim3(256), 0, stream,
                       cnt, off, bsum, N_NODES_C);
    hipLaunchKernelGGL(scan_bsum, dim3(1), dim3(512), 0, stream, bsum, NB_N);
    hipLaunchKernelGGL(scan_add, dim3(NB_N), dim3(256), 0, stream,
                       off, bsum, N_NODES_C, N_EDGES_C);
    hipLaunchKernelGGL(placeP_kernel, dim3(NB_E), dim3(256), 0, stream,
                       edge_index, off, cnt, perm);
    hipLaunchKernelGGL(xcast_kernel, dim3((N_NODES_C * 2 + 255) / 256), dim3(256),
                       0, stream, node_features, xb);
    hipLaunchKernelGGL(msg_kernel, dim3(2048), dim3(256), 0, stream,
                       edge_index, edge_attr, W_msg_tp, xb, msgb);
    hipLaunchKernelGGL(agg4_kernel, dim3(NB_G), dim3(256), 0, stream,
                       W_msg_lin, perm, msgb, off, agg);
    hipLaunchKernelGGL(node_kernel, dim3(NB_N), dim3(256), 0, stream,
                       node_features, agg, W_upd_tp, W_upd_lin, out);
  } else if (ws_size >= B_NEED) {
    int*   off  = (int*)(ws + B_OFF);
    int*   cnt  = (int*)(ws + B_CNT);
    int*   bsum = (int*)(ws + B_BSUM);
    int*   colp = (int*)(ws + B_COLP);
    uint4* eab  = (uint4*)(ws + B_EAB);
    uint4* Tb   = (uint4*)(ws + B_T);
    float* agg  = (float*)(ws + B_AGG);

    hipLaunchKernelGGL(zero_ints, dim3(NB_N), dim3(256), 0, stream, cnt, N_NODES_C);
    hipLaunchKernelGGL(hist_kernel, dim3(NB_E), dim3(256), 0, stream, edge_index, cnt);
    hipLaunchKernelGGL(scan_block, dim3(NB_N), dim3(256), 0, stream,
                       cnt, off, bsum, N_NODES_C);
    hipLaunchKernelGGL(scan_bsum, dim3(1), dim3(512), 0, stream, bsum, NB_N);
    hipLaunchKernelGGL(scan_add, dim3(NB_N), dim3(256), 0, stream,
                       off, bsum, N_NODES_C, N_EDGES_C);
    hipLaunchKernelGGL(place_kernel, dim3(NB_E), dim3(256), 0, stream,
                       edge_index, edge_attr, off, cnt, colp, eab);
    hipLaunchKernelGGL(tbuild_kernel, dim3(NB_G), dim3(256), 0, stream,
                       node_features, W_msg_tp, Tb);
    hipLaunchKernelGGL(agg2_kernel, dim3(NB_G), dim3(256), 0, stream,
                       W_msg_lin, colp, eab, Tb, off, agg);
    hipLaunchKernelGGL(node_kernel, dim3(NB_N), dim3(256), 0, stream,
                       node_features, agg, W_upd_tp, W_upd_lin, out);
  } else {
    float* agg = (float*)ws;
    const int n4 = N_NODES_C * 16 / 4;
    hipLaunchKernelGGL(zero_f4, dim3((n4 + 255) / 256), dim3(256), 0, stream,
                       (float4*)agg, n4);
    hipLaunchKernelGGL(edge_kernel, dim3(N_EDGES_C / (256 * EPT)), dim3(256), 0, stream,
                       node_features, edge_attr, W_msg_tp, W_msg_lin, edge_index, agg);
    hipLaunchKernelGGL(node_kernel, dim3(NB_N), dim3(256), 0, stream,
                       node_features, agg, W_upd_tp, W_upd_lin, out);
  }
}

// Round 11
// 374.868 us; speedup vs baseline: 1.4358x; 1.4358x over previous
//
#include <hip/hip_runtime.h>
#include <math.h>

#define N_NODES_C 100000
#define N_EDGES_C 3200000
// D_NODE=16, D_EDGE=8, D_HIDDEN=16

#define NORM_MSG_TP 0.08838834764831845f   // 1/sqrt(16*8)
#define NORM_UPD_TP 0.0625f                // 1/sqrt(16*16)
#define NORM_LIN    0.25f                  // 1/sqrt(16)

typedef float f32x4 __attribute__((ext_vector_type(4)));
typedef short bf16x8 __attribute__((ext_vector_type(8)));
typedef int   int4v  __attribute__((ext_vector_type(4)));

__device__ __forceinline__ float silu_f(float v) {
  return v / (1.0f + __expf(-v));
}

__device__ __forceinline__ void atomic_add_hw(float* p, float v) {
  unsafeAtomicAdd(p, v);
}

// float -> bf16 bits (round to nearest even)
__device__ __forceinline__ unsigned int bf16_bits(float f) {
  unsigned int b = __float_as_uint(f);
  return (b + 0x7fffu + ((b >> 16) & 1u)) >> 16;
}
__device__ __forceinline__ unsigned int pack_bf16x2(float lo, float hi) {
  return bf16_bits(lo) | (bf16_bits(hi) << 16);
}
__device__ __forceinline__ float unlo(unsigned int w) { return __uint_as_float(w << 16); }
__device__ __forceinline__ float unhi(unsigned int w) { return __uint_as_float(w & 0xffff0000u); }

// ---------------- CSR build ----------------

__global__ __launch_bounds__(256) void zero_ints(int* __restrict__ p, int n) {
  int i = blockIdx.x * 256 + threadIdx.x;
  if (i < n) p[i] = 0;
}

// returning histogram: pos[e] = 0-based rank of edge e within its dest row
__global__ __launch_bounds__(256) void hist_kernel(
    const int* __restrict__ row, int* __restrict__ cnt, int* __restrict__ pos) {
  int e = blockIdx.x * 256 + threadIdx.x;   // grid exact: E/256
  pos[e] = atomicAdd(&cnt[row[e]], 1);
}

__global__ __launch_bounds__(256) void scan_block(
    const int* __restrict__ cnt, int* __restrict__ off, int* __restrict__ bsum, int n) {
  __shared__ int s[256];
  const int t = threadIdx.x;
  const int i = blockIdx.x * 256 + t;
  const int v = (i < n) ? cnt[i] : 0;
  s[t] = v;
  __syncthreads();
#pragma unroll
  for (int o = 1; o < 256; o <<= 1) {
    int tv = (t >= o) ? s[t - o] : 0;
    __syncthreads();
    s[t] += tv;
    __syncthreads();
  }
  if (i < n) off[i] = s[t] - v;
  if (t == 255) bsum[blockIdx.x] = s[255];
}

__global__ void scan_bsum(int* __restrict__ bsum, int nb) {
  __shared__ int s[512];
  const int t = threadIdx.x;
  const int v = (t < nb) ? bsum[t] : 0;
  s[t] = v;
  __syncthreads();
#pragma unroll
  for (int o = 1; o < 512; o <<= 1) {
    int tv = (t >= o) ? s[t - o] : 0;
    __syncthreads();
    s[t] += tv;
    __syncthreads();
  }
  if (t < nb) bsum[t] = s[t] - v;
}

__global__ __launch_bounds__(256) void scan_add(
    int* __restrict__ off, const int* __restrict__ bsum, int n, int total) {
  int i = blockIdx.x * 256 + threadIdx.x;
  if (i < n) off[i] += bsum[blockIdx.x];
  if (i == 0) off[n] = total;
}

// ---------------- x -> bf16 table (3.2 MB, L2-resident) ----------------

__global__ __launch_bounds__(256) void xcast_kernel(
    const float* __restrict__ x, unsigned short* __restrict__ xb) {
  const int i = blockIdx.x * 256 + threadIdx.x;   // one thread per 8 elems
  if (i < N_NODES_C * 2) {
    const float4 a = *reinterpret_cast<const float4*>(x + (size_t)i * 8);
    const float4 b = *reinterpret_cast<const float4*>(x + (size_t)i * 8 + 4);
    uint4 w;
    w.x = pack_bf16x2(a.x, a.y); w.y = pack_bf16x2(a.z, a.w);
    w.z = pack_bf16x2(b.x, b.y); w.w = pack_bf16x2(b.z, b.w);
    *reinterpret_cast<uint4*>(xb + (size_t)i * 8) = w;
  }
}

// ---------------- place4: pipelined MFMA message + sorted scatter (no atomics) ----------------
// Slot p = off[row] + pos[e] (precomputed by returning hist): the claim chain is
// two cheap reads. 2-deep pipeline on the eidx -> xb chain. nt scatter store.

#define CLAIM_TILE(T, CC, PP) do {                                   \
    const int e_ = (T) * 16 + r;                                     \
    if (g == 0) {                                                    \
      CC = eidx[N_EDGES_C + e_];                                     \
      PP = off[eidx[e_]] + pos[e_];                                  \
    }                                                                \
  } while (0)

#define GATH_TILE(T, CC, XH, F4) do {                                \
    const int e_ = (T) * 16 + r;                                     \
    const int c_ = __shfl(CC, r);                                    \
    if (g < 2) {                                                     \
      XH = *reinterpret_cast<const uint4*>(xb + (size_t)c_ * 16 + g * 8); \
      F4 = *reinterpret_cast<const float4*>(ea + (size_t)e_ * 8 + g * 4); \
    }                                                                \
  } while (0)

__global__ __launch_bounds__(256) void place4_kernel(
    const int*   __restrict__ eidx,   // [2,E]
    const float* __restrict__ ea,     // [E,8] fp32
    const float* __restrict__ Wtp,    // [16,8,16]
    const int*   __restrict__ off,    // [N+1]
    const int*   __restrict__ pos,    // [E] rank within row
    const unsigned short* __restrict__ xb,  // [N,16] bf16
    unsigned int* __restrict__ msort) // [E*8] words: slot p = 32B bf16x16
{
  __shared__ float sm[4][16][20];     // stride 20: 16B-aligned rows, 2-way banks
  const int lane  = threadIdx.x & 63;
  const int wv    = threadIdx.x >> 6;
  const int r     = lane & 15;
  const int g     = lane >> 4;
  const int gsel  = g >> 1;
  const int ghalf = g & 1;

  // B frag: bq[q][t] = Wtp[i=8*ghalf+t][j=2q+gsel][h=r]  (K reordered k=j*16+i)
  bf16x8 bq[4];
#pragma unroll
  for (int q = 0; q < 4; ++q) {
#pragma unroll
    for (int t = 0; t < 8; ++t) {
      const float w = Wtp[(8 * ghalf + t) * 128 + (2 * q + gsel) * 16 + r];
      bq[q][t] = (short)bf16_bits(w);
    }
  }

  const int s = gridDim.x * 4;
  const int wid = blockIdx.x * 4 + wv;
  const int ntiles = N_EDGES_C / 16;  // 200000

  int cc_a = 0, pp_a = 0, cc_b = 0, pp_b = 0;
  uint4 xh_a; xh_a.x = xh_a.y = xh_a.z = xh_a.w = 0;
  float4 f4_a = make_float4(0.f, 0.f, 0.f, 0.f);

  if (wid < ntiles)     CLAIM_TILE(wid, cc_a, pp_a);
  if (wid + s < ntiles) CLAIM_TILE(wid + s, cc_b, pp_b);
  if (wid < ntiles)     GATH_TILE(wid, cc_a, xh_a, f4_a);

  for (int t = wid; t < ntiles; t += s) {
    // depth-2 prefetch: slot + column index
    int cc_c = 0, pp_c = 0;
    if (t + 2 * s < ntiles) CLAIM_TILE(t + 2 * s, cc_c, pp_c);
    // depth-1 prefetch: gathers
    uint4 xh_b; xh_b.x = xh_b.y = xh_b.z = xh_b.w = 0;
    float4 f4_b = make_float4(0.f, 0.f, 0.f, 0.f);
    if (t + s < ntiles) GATH_TILE(t + s, cc_b, xh_b, f4_b);

    // ---- compute tile t ----
    uint4 xh;
    xh.x = (unsigned)__shfl((int)xh_a.x, ghalf * 16 + r);
    xh.y = (unsigned)__shfl((int)xh_a.y, ghalf * 16 + r);
    xh.z = (unsigned)__shfl((int)xh_a.z, ghalf * 16 + r);
    xh.w = (unsigned)__shfl((int)xh_a.w, ghalf * 16 + r);
    float xf[8];
    xf[0] = unlo(xh.x); xf[1] = unhi(xh.x);
    xf[2] = unlo(xh.y); xf[3] = unhi(xh.y);
    xf[4] = unlo(xh.z); xf[5] = unhi(xh.z);
    xf[6] = unlo(xh.w); xf[7] = unhi(xh.w);
    const float a0 = __shfl(f4_a.x, r),      a1 = __shfl(f4_a.y, r);
    const float a2 = __shfl(f4_a.z, r),      a3 = __shfl(f4_a.w, r);
    const float b0 = __shfl(f4_a.x, 16 + r), b1 = __shfl(f4_a.y, 16 + r);
    const float b2 = __shfl(f4_a.z, 16 + r), b3 = __shfl(f4_a.w, 16 + r);
    float eq[4];
    eq[0] = gsel ? a1 : a0;  eq[1] = gsel ? a3 : a2;
    eq[2] = gsel ? b1 : b0;  eq[3] = gsel ? b3 : b2;

    f32x4 acc = {0.f, 0.f, 0.f, 0.f};
#pragma unroll
    for (int q = 0; q < 4; ++q) {
      const float e_ = eq[q];
      const unsigned u0 = __float_as_uint(xf[0] * e_) + 0x8000u;
      const unsigned u1 = __float_as_uint(xf[1] * e_) + 0x8000u;
      const unsigned u2 = __float_as_uint(xf[2] * e_) + 0x8000u;
      const unsigned u3 = __float_as_uint(xf[3] * e_) + 0x8000u;
      const unsigned u4 = __float_as_uint(xf[4] * e_) + 0x8000u;
      const unsigned u5 = __float_as_uint(xf[5] * e_) + 0x8000u;
      const unsigned u6 = __float_as_uint(xf[6] * e_) + 0x8000u;
      const unsigned u7 = __float_as_uint(xf[7] * e_) + 0x8000u;
      int4v iv;
      iv.x = (int)__builtin_amdgcn_perm(u1, u0, 0x07060302u);
      iv.y = (int)__builtin_amdgcn_perm(u3, u2, 0x07060302u);
      iv.z = (int)__builtin_amdgcn_perm(u5, u4, 0x07060302u);
      iv.w = (int)__builtin_amdgcn_perm(u7, u6, 0x07060302u);
      union { int4v i; bf16x8 h; } cv; cv.i = iv;
      acc = __builtin_amdgcn_mfma_f32_16x16x32_bf16(cv.h, bq[q], acc, 0, 0, 0);
    }

    // silu + 16x16 transpose via padded per-wave LDS tile
#pragma unroll
    for (int j2 = 0; j2 < 4; ++j2)
      sm[wv][g * 4 + j2][r] = silu_f(acc[j2] * NORM_MSG_TP);

    asm volatile("s_waitcnt lgkmcnt(0)" ::: "memory");
    __builtin_amdgcn_sched_barrier(0);

    const int rr  = lane >> 2;
    const int wsl = lane & 3;
    const float4 v4 = *reinterpret_cast<const float4*>(&sm[wv][rr][wsl * 4]);
    const int prr = __shfl(pp_a, rr);
    const unsigned long long wout =
        (unsigned long long)pack_bf16x2(v4.x, v4.y) |
        ((unsigned long long)pack_bf16x2(v4.z, v4.w) << 32);
    // nt store: bypass L2 allocation (cross-XCD line thrash), stream to L3
    __builtin_nontemporal_store(
        wout, reinterpret_cast<unsigned long long*>(&msort[(size_t)prr * 8 + wsl * 2]));

    // rotate pipeline state
    pp_a = pp_b; xh_a = xh_b; f4_a = f4_b;
    cc_b = cc_c; pp_b = pp_c;
  }
}

// ---------------- agg3: linear segment-sum of sorted messages + Wlin ----------------

__global__ __launch_bounds__(256) void agg3_kernel(
    const float* __restrict__ Wlin,   // [16,16]
    const unsigned int* __restrict__ msort,  // [E*8]
    const int*   __restrict__ off,    // [N+1]
    float*       __restrict__ agg)    // [N,16]
{
  __shared__ float sL[256];
  if (threadIdx.x < 256) sL[threadIdx.x] = Wlin[threadIdx.x];
  __syncthreads();

  const int slane = threadIdx.x & 15;
  const int n = blockIdx.x * 16 + (threadIdx.x >> 4);   // grid exact: N/16

  const int off0 = off[n];
  const int off1 = off[n + 1];

  float acc = 0.f;
  for (int p = off0; p < off1; ++p) {
    const unsigned int w = msort[(size_t)p * 8 + (slane >> 1)];
    acc += (slane & 1) ? unhi(w) : unlo(w);
  }

  float a = 0.f;
#pragma unroll
  for (int h = 0; h < 16; ++h) {
    const float v = __shfl(acc, h, 16);
    a = fmaf(v, sL[h * 16 + slane], a);
  }
  agg[(size_t)n * 16 + slane] = a * NORM_LIN;
}

// ---------------- Tier B (R6): eab/colp split path ----------------

__global__ __launch_bounds__(256) void tbuild_kernel(
    const float* __restrict__ x, const float* __restrict__ Wtp,
    uint4* __restrict__ Tb)
{
  __shared__ float sWT[16 * 132];
  for (int idx = threadIdx.x; idx < 2048; idx += 256) {
    const int i = idx >> 7, j = (idx >> 4) & 7, h = idx & 15;
    sWT[h * 132 + i * 8 + j] = Wtp[idx];
  }
  __syncthreads();

  const int slane = threadIdx.x & 15;
  const int n = blockIdx.x * 16 + (threadIdx.x >> 4);

  float xr[16];
  const float4* xp = reinterpret_cast<const float4*>(x + (size_t)n * 16);
#pragma unroll
  for (int q = 0; q < 4; ++q) {
    float4 v = xp[q];
    xr[q*4+0] = v.x; xr[q*4+1] = v.y; xr[q*4+2] = v.z; xr[q*4+3] = v.w;
  }

  float t[8];
#pragma unroll
  for (int j = 0; j < 8; ++j) t[j] = 0.f;
#pragma unroll
  for (int i = 0; i < 16; ++i) {
    const float xi = xr[i];
    const float4 wa = *reinterpret_cast<const float4*>(&sWT[slane * 132 + i * 8]);
    const float4 wb = *reinterpret_cast<const float4*>(&sWT[slane * 132 + i * 8 + 4]);
    t[0] = fmaf(xi, wa.x, t[0]); t[1] = fmaf(xi, wa.y, t[1]);
    t[2] = fmaf(xi, wa.z, t[2]); t[3] = fmaf(xi, wa.w, t[3]);
    t[4] = fmaf(xi, wb.x, t[4]); t[5] = fmaf(xi, wb.y, t[5]);
    t[6] = fmaf(xi, wb.z, t[6]); t[7] = fmaf(xi, wb.w, t[7]);
  }
  uint4 w;
  w.x = pack_bf16x2(t[0], t[1]);
  w.y = pack_bf16x2(t[2], t[3]);
  w.z = pack_bf16x2(t[4], t[5]);
  w.w = pack_bf16x2(t[6], t[7]);
  Tb[(size_t)n * 16 + slane] = w;
}

__global__ __launch_bounds__(256) void place_kernel(
    const int* __restrict__ eidx, const float* __restrict__ ea,
    const int* __restrict__ off, int* __restrict__ cnt,
    int* __restrict__ colp, uint4* __restrict__ eab) {
  int e = blockIdx.x * 256 + threadIdx.x;
  const int r = eidx[e];
  const int old = atomicSub(&cnt[r], 1);
  const int p = off[r] + old - 1;
  colp[p] = eidx[N_EDGES_C + e];
  const float4* ep = reinterpret_cast<const float4*>(ea + (size_t)e * 8);
  const float4 a = ep[0];
  const float4 b = ep[1];
  uint4 w;
  w.x = pack_bf16x2(a.x, a.y);
  w.y = pack_bf16x2(a.z, a.w);
  w.z = pack_bf16x2(b.x, b.y);
  w.w = pack_bf16x2(b.z, b.w);
  eab[p] = w;
}

__global__ __launch_bounds__(256) void agg2_kernel(
    const float* __restrict__ Wlin, const int* __restrict__ colp,
    const uint4* __restrict__ eab, const uint4* __restrict__ Tb,
    const int* __restrict__ off, float* __restrict__ agg)
{
  __shared__ float sL[256];
  if (threadIdx.x < 256) sL[threadIdx.x] = Wlin[threadIdx.x];
  __syncthreads();

  const int slane = threadIdx.x & 15;
  const int n = blockIdx.x * 16 + (threadIdx.x >> 4);

  const int off0 = off[n];
  const int off1 = off[n + 1];

  float acc = 0.f;
#pragma unroll 2
  for (int p = off0; p < off1; ++p) {
    const int c = colp[p];
    const uint4 tw = Tb[(size_t)c * 16 + slane];
    const uint4 ew = eab[p];
    float m;
    m  = unlo(ew.x) * unlo(tw.x);
    m  = fmaf(unhi(ew.x), unhi(tw.x), m);
    m  = fmaf(unlo(ew.y), unlo(tw.y), m);
    m  = fmaf(unhi(ew.y), unhi(tw.y), m);
    m  = fmaf(unlo(ew.z), unlo(tw.z), m);
    m  = fmaf(unhi(ew.z), unhi(tw.z), m);
    m  = fmaf(unlo(ew.w), unlo(tw.w), m);
    m  = fmaf(unhi(ew.w), unhi(tw.w), m);
    acc += silu_f(m * NORM_MSG_TP);
  }

  float a = 0.f;
#pragma unroll
  for (int h = 0; h < 16; ++h) {
    const float v = __shfl(acc, h, 16);
    a = fmaf(v, sL[h * 16 + slane], a);
  }
  agg[(size_t)n * 16 + slane] = a * NORM_LIN;
}

// ---------------- node update ----------------

__global__ __launch_bounds__(256) void node_kernel(
    const float* __restrict__ x, const float* __restrict__ agg,
    const float* __restrict__ Wtp, const float* __restrict__ Wlin,
    float* __restrict__ out)
{
  __shared__ float sW[4096];
  __shared__ float sL[256];
  for (int t = threadIdx.x; t < 4096; t += 256) sW[t] = Wtp[t];
  sL[threadIdx.x] = Wlin[threadIdx.x];
  __syncthreads();

  const long n = (long)blockIdx.x * 256 + threadIdx.x;
  if (n >= N_NODES_C) return;

  float xr[16], ar[16];
  const float4* xp = reinterpret_cast<const float4*>(x + (size_t)n * 16);
  const float4* ap = reinterpret_cast<const float4*>(agg + (size_t)n * 16);
#pragma unroll
  for (int q = 0; q < 4; ++q) {
    float4 v = xp[q];
    xr[q*4+0] = v.x; xr[q*4+1] = v.y; xr[q*4+2] = v.z; xr[q*4+3] = v.w;
    float4 w = ap[q];
    ar[q*4+0] = w.x; ar[q*4+1] = w.y; ar[q*4+2] = w.z; ar[q*4+3] = w.w;
  }
  float u[16];
#pragma unroll
  for (int k = 0; k < 16; ++k) u[k] = 0.f;
#pragma unroll
  for (int i = 0; i < 16; ++i) {
#pragma unroll
    for (int h = 0; h < 16; ++h) {
      const float p = xr[i] * ar[h];
      const float* w = &sW[(i*16 + h) * 16];
#pragma unroll
      for (int k = 0; k < 16; ++k) u[k] = fmaf(p, w[k], u[k]);
    }
  }
  float g[16];
#pragma unroll
  for (int k = 0; k < 16; ++k) g[k] = silu_f(u[k] * NORM_UPD_TP);
  float res[16];
#pragma unroll
  for (int k2 = 0; k2 < 16; ++k2) {
    float a = 0.f;
#pragma unroll
    for (int k = 0; k < 16; ++k) a = fmaf(g[k], sL[k*16 + k2], a);
    res[k2] = xr[k2] + a * NORM_LIN;
  }
  float4* op = reinterpret_cast<float4*>(out + (size_t)n * 16);
#pragma unroll
  for (int q = 0; q < 4; ++q)
    op[q] = make_float4(res[q*4+0], res[q*4+1], res[q*4+2], res[q*4+3]);
}

// ---------------- Tier C fallback: atomic scatter ----------------

__global__ void zero_f4(float4* __restrict__ p, int n4) {
  int i = blockIdx.x * blockDim.x + threadIdx.x;
  if (i < n4) p[i] = make_float4(0.f, 0.f, 0.f, 0.f);
}

#define EPT 2
__global__ __launch_bounds__(256) void edge_kernel(
    const float* __restrict__ x, const float* __restrict__ ea,
    const float* __restrict__ Wtp, const float* __restrict__ Wlin,
    const int* __restrict__ eidx, float* __restrict__ agg)
{
  __shared__ float sW[2048];
  __shared__ float sL[256];
  for (int t = threadIdx.x; t < 2048; t += 256) sW[t] = Wtp[t];
  sL[threadIdx.x] = Wlin[threadIdx.x];
  __syncthreads();
  const long e0 = ((long)blockIdx.x * 256 + threadIdx.x) * EPT;
  float xr[EPT][16], er[EPT][8];
  int rw[EPT];
#pragma unroll
  for (int e = 0; e < EPT; ++e) {
    const long ei = e0 + e;
    const int c = eidx[N_EDGES_C + ei];
    rw[e] = eidx[ei];
    const float4* xp = reinterpret_cast<const float4*>(x + (size_t)c * 16);
#pragma unroll
    for (int q = 0; q < 4; ++q) {
      float4 v = xp[q];
      xr[e][q*4+0] = v.x; xr[e][q*4+1] = v.y; xr[e][q*4+2] = v.z; xr[e][q*4+3] = v.w;
    }
    const float4* ep = reinterpret_cast<const float4*>(ea + (size_t)ei * 8);
#pragma unroll
    for (int q = 0; q < 2; ++q) {
      float4 v = ep[q];
      er[e][q*4+0] = v.x; er[e][q*4+1] = v.y; er[e][q*4+2] = v.z; er[e][q*4+3] = v.w;
    }
  }
  float m[EPT][16];
#pragma unroll
  for (int e = 0; e < EPT; ++e)
#pragma unroll
    for (int h = 0; h < 16; ++h) m[e][h] = 0.f;
#pragma unroll
  for (int i = 0; i < 16; ++i) {
#pragma unroll
    for (int j = 0; j < 8; ++j) {
      float p[EPT];
#pragma unroll
      for (int e = 0; e < EPT; ++e) p[e] = xr[e][i] * er[e][j];
      const float* w = &sW[(i*8 + j) * 16];
#pragma unroll
      for (int h = 0; h < 16; ++h) {
        const float wv = w[h];
#pragma unroll
        for (int e = 0; e < EPT; ++e) m[e][h] = fmaf(p[e], wv, m[e][h]);
      }
    }
  }
#pragma unroll
  for (int e = 0; e < EPT; ++e) {
    float g[16];
#pragma unroll
    for (int h = 0; h < 16; ++h) g[h] = silu_f(m[e][h] * NORM_MSG_TP);
    float* ap = agg + (size_t)rw[e] * 16;
#pragma unroll
    for (int h2 = 0; h2 < 16; ++h2) {
      float a = 0.f;
#pragma unroll
      for (int h = 0; h < 16; ++h) a = fmaf(g[h], sL[h*16 + h2], a);
      atomic_add_hw(ap + h2, a * NORM_LIN);
    }
  }
}

// ---------------- launch ----------------

extern "C" void kernel_launch(void* const* d_in, const int* in_sizes, int n_in,
                              void* d_out, int out_size, void* d_ws, size_t ws_size,
                              hipStream_t stream) {
  const float* node_features = (const float*)d_in[0];
  const float* edge_attr     = (const float*)d_in[1];
  const float* W_msg_tp      = (const float*)d_in[3];
  const float* W_msg_lin     = (const float*)d_in[4];
  const float* W_upd_tp      = (const float*)d_in[5];
  const float* W_upd_lin     = (const float*)d_in[6];
  const int*   edge_index    = (const int*)d_in[7];
  float* out = (float*)d_out;
  char* ws = (char*)d_ws;

  const int NB_N = (N_NODES_C + 255) / 256;           // 391
  const int NB_E = N_EDGES_C / 256;                   // 12500 exact
  const int NB_G = N_NODES_C / 16;                    // 6250 exact

  // ---- Tier A4: fused MFMA msort, no-atomic place (119.2 MB) ----
  // pos dies after place4; agg (6.4 MB) aliases its region.
  const size_t A_OFF  = 0;                            // (N+1) ints
  const size_t A_CNT  = 400128;                       // N ints
  const size_t A_BSUM = 800256;                       // 512 ints
  const size_t A_POS  = 802304;                       // E ints (12.8 MB); agg aliases
  const size_t A_MSORT= A_POS + 12800000;             // E*8 uint (102.4 MB)
  const size_t A_XB   = A_MSORT + 102400000;          // N*16 ushort (3.2 MB)
  const size_t A_NEED = A_XB + 3200000;               // 119,202,304 B

  // ---- Tier B layout: R6 path (96.8 MB) ----
  const size_t B_OFF  = 0;
  const size_t B_CNT  = 400128;
  const size_t B_BSUM = 800256;
  const size_t B_COLP = 804352;
  const size_t B_EAB  = B_COLP + 12800000;
  const size_t B_T    = B_EAB + 51200000;
  const size_t B_AGG  = B_T + 25600000;
  const size_t B_NEED = B_AGG + 6400000;

  if (ws_size >= A_NEED) {
    int*   off   = (int*)(ws + A_OFF);
    int*   cnt   = (int*)(ws + A_CNT);
    int*   bsum  = (int*)(ws + A_BSUM);
    int*   pos   = (int*)(ws + A_POS);
    unsigned int* msort = (unsigned int*)(ws + A_MSORT);
    unsigned short* xb  = (unsigned short*)(ws + A_XB);
    float* agg   = (float*)(ws + A_POS);              // alias: pos dead after place4

    hipLaunchKernelGGL(zero_ints, dim3(NB_N), dim3(256), 0, stream, cnt, N_NODES_C);
    hipLaunchKernelGGL(hist_kernel, dim3(NB_E), dim3(256), 0, stream,
                       edge_index, cnt, pos);
    hipLaunchKernelGGL(scan_block, dim3(NB_N), dim3(256), 0, stream,
                       cnt, off, bsum, N_NODES_C);
    hipLaunchKernelGGL(scan_bsum, dim3(1), dim3(512), 0, stream, bsum, NB_N);
    hipLaunchKernelGGL(scan_add, dim3(NB_N), dim3(256), 0, stream,
                       off, bsum, N_NODES_C, N_EDGES_C);
    hipLaunchKernelGGL(xcast_kernel, dim3((N_NODES_C * 2 + 255) / 256), dim3(256),
                       0, stream, node_features, xb);
    hipLaunchKernelGGL(place4_kernel, dim3(2048), dim3(256), 0, stream,
                       edge_index, edge_attr, W_msg_tp, off, pos, xb, msort);
    hipLaunchKernelGGL(agg3_kernel, dim3(NB_G), dim3(256), 0, stream,
                       W_msg_lin, msort, off, agg);
    hipLaunchKernelGGL(node_kernel, dim3(NB_N), dim3(256), 0, stream,
                       node_features, agg, W_upd_tp, W_upd_lin, out);
  } else if (ws_size >= B_NEED) {
    int*   off  = (int*)(ws + B_OFF);
    int*   cnt  = (int*)(ws + B_CNT);
    int*   bsum = (int*)(ws + B_BSUM);
    int*   colp = (int*)(ws + B_COLP);
    uint4* eab  = (uint4*)(ws + B_EAB);
    uint4* Tb   = (uint4*)(ws + B_T);
    float* agg  = (float*)(ws + B_AGG);

    hipLaunchKernelGGL(zero_ints, dim3(NB_N), dim3(256), 0, stream, cnt, N_NODES_C);
    hipLaunchKernelGGL(hist_kernel, dim3(NB_E), dim3(256), 0, stream,
                       edge_index, cnt, colp /*scratch pos*/);
    hipLaunchKernelGGL(scan_block, dim3(NB_N), dim3(256), 0, stream,
                       cnt, off, bsum, N_NODES_C);
    hipLaunchKernelGGL(scan_bsum, dim3(1), dim3(512), 0, stream, bsum, NB_N);
    hipLaunchKernelGGL(scan_add, dim3(NB_N), dim3(256), 0, stream,
                       off, bsum, N_NODES_C, N_EDGES_C);
    hipLaunchKernelGGL(place_kernel, dim3(NB_E), dim3(256), 0, stream,
                       edge_index, edge_attr, off, cnt, colp, eab);
    hipLaunchKernelGGL(tbuild_kernel, dim3(NB_G), dim3(256), 0, stream,
                       node_features, W_msg_tp, Tb);
    hipLaunchKernelGGL(agg2_kernel, dim3(NB_G), dim3(256), 0, stream,
                       W_msg_lin, colp, eab, Tb, off, agg);
    hipLaunchKernelGGL(node_kernel, dim3(NB_N), dim3(256), 0, stream,
                       node_features, agg, W_upd_tp, W_upd_lin, out);
  } else {
    float* agg = (float*)ws;
    const int n4 = N_NODES_C * 16 / 4;
    hipLaunchKernelGGL(zero_f4, dim3((n4 + 255) / 256), dim3(256), 0, stream,
                       (float4*)agg, n4);
    hipLaunchKernelGGL(edge_kernel, dim3(N_EDGES_C / (256 * EPT)), dim3(256), 0, stream,
                       node_features, edge_attr, W_msg_tp, W_msg_lin, edge_index, agg);
    hipLaunchKernelGGL(node_kernel, dim3(NB_N), dim3(256), 0, stream,
                       node_features, agg, W_upd_tp, W_upd_lin, out);
  }
}